// Round 1
// baseline (399.004 us; speedup 1.0000x reference)
//
#include <hip/hip_runtime.h>
#include <cstdint>
#include <cstddef>

#define B_ 4
#define M_ 4096
#define N_ 4096
#define F_ 8
#define H_ 128
#define O_ 8

// round-to-nearest-even float -> bf16 (as uint16 in low bits)
__device__ __forceinline__ uint32_t f2bf1(float x) {
    uint32_t u = __float_as_uint(x);
    return (u + 0x7fffu + ((u >> 16) & 1u)) >> 16;
}

// decode 8 packed bf16 (uint4) -> 8 floats; f[0] is low half of w.x
__device__ __forceinline__ void bf8dec(uint4 w, float* f) {
    f[0] = __uint_as_float(w.x << 16);
    f[1] = __uint_as_float(w.x & 0xffff0000u);
    f[2] = __uint_as_float(w.y << 16);
    f[3] = __uint_as_float(w.y & 0xffff0000u);
    f[4] = __uint_as_float(w.z << 16);
    f[5] = __uint_as_float(w.z & 0xffff0000u);
    f[6] = __uint_as_float(w.w << 16);
    f[7] = __uint_as_float(w.w & 0xffff0000u);
}

__device__ __forceinline__ float elu(float x) {
    return x > 0.f ? x : (__expf(x) - 1.f);
}

// ---------------------------------------------------------------------------
// Kernel 1: bmat[b][m][f] = sum_n adj[b][m][n] * feat[b][n][f]
// grid = B*256 blocks, 256 threads (4 waves). Block: one batch, 16 rows.
// feat[b] staged in LDS as bf16, 4-plane layout: plane k holds n with n%4==k
// at index n/4, so per-chunk reads are lane-consecutive (conflict-free).
// ---------------------------------------------------------------------------
__global__ __launch_bounds__(256, 2)
void k_adjfeat(const float* __restrict__ adj, const float* __restrict__ feat,
               float* __restrict__ bmat) {
    __shared__ uint4 sfeat[N_];  // 4096 * 16B = 64 KB

    const int tid = threadIdx.x;
    const int bb  = blockIdx.x >> 8;   // batch
    const int rb  = blockIdx.x & 255;  // row-block (16 rows)

    // ---- stage feat[bb] -> bf16 LDS (4-plane layout) ----
    const float4* fsrc = (const float4*)(feat + (size_t)bb * (N_ * F_));
    for (int n = tid; n < N_; n += 256) {
        float4 lo = fsrc[2 * n];
        float4 hi = fsrc[2 * n + 1];
        uint4 w;
        w.x = f2bf1(lo.x) | (f2bf1(lo.y) << 16);
        w.y = f2bf1(lo.z) | (f2bf1(lo.w) << 16);
        w.z = f2bf1(hi.x) | (f2bf1(hi.y) << 16);
        w.w = f2bf1(hi.z) | (f2bf1(hi.w) << 16);
        sfeat[(n & 3) * 1024 + (n >> 2)] = w;
    }
    __syncthreads();

    const int lane = tid & 63;
    const int wv   = tid >> 6;
    const int m0   = rb * 16 + wv * 4;  // this wave's 4 rows

    const float4* arow = (const float4*)(adj + (size_t)(bb * M_ + m0) * N_);

    float acc[4][8];
#pragma unroll
    for (int r = 0; r < 4; ++r)
#pragma unroll
        for (int f = 0; f < 8; ++f) acc[r][f] = 0.f;

#pragma unroll 1
    for (int c = 0; c < 16; ++c) {
        const int ni = (c << 6) + lane;  // float4 index within the row
        float4 a0 = arow[ni];
        float4 a1 = arow[ni + 1024];
        float4 a2 = arow[ni + 2048];
        float4 a3 = arow[ni + 3072];
        uint4 w0 = sfeat[ni];
        uint4 w1 = sfeat[1024 + ni];
        uint4 w2 = sfeat[2048 + ni];
        uint4 w3 = sfeat[3072 + ni];

        float av[4][4] = {{a0.x, a1.x, a2.x, a3.x},
                          {a0.y, a1.y, a2.y, a3.y},
                          {a0.z, a1.z, a2.z, a3.z},
                          {a0.w, a1.w, a2.w, a3.w}};
        uint4 ww[4] = {w0, w1, w2, w3};
#pragma unroll
        for (int k = 0; k < 4; ++k) {
            float f[8];
            bf8dec(ww[k], f);
#pragma unroll
            for (int r = 0; r < 4; ++r) {
                const float a = av[k][r];
#pragma unroll
                for (int j = 0; j < 8; ++j)
                    acc[r][j] = fmaf(a, f[j], acc[r][j]);
            }
        }
    }

    // ---- 64-lane butterfly reduction (every lane ends with full sums) ----
#pragma unroll
    for (int r = 0; r < 4; ++r)
#pragma unroll
        for (int j = 0; j < 8; ++j) {
            float v = acc[r][j];
            v += __shfl_xor(v, 32, 64);
            v += __shfl_xor(v, 16, 64);
            v += __shfl_xor(v, 8, 64);
            v += __shfl_xor(v, 4, 64);
            v += __shfl_xor(v, 2, 64);
            v += __shfl_xor(v, 1, 64);
            acc[r][j] = v;
        }

    // lane (r*8+f) writes b[m0+r][f] -> one coalesced 128B store of 32 lanes
    float my = 0.f;
#pragma unroll
    for (int r = 0; r < 4; ++r)
#pragma unroll
        for (int j = 0; j < 8; ++j)
            if (lane == r * 8 + j) my = acc[r][j];
    if (lane < 32)
        bmat[(size_t)(bb * M_ + m0 + (lane >> 3)) * 8 + (lane & 7)] = my;
}

// ---------------------------------------------------------------------------
// Kernel 2: MLP over 16384 rows of b (flat [B*M, 8]) -> out [B*M, 8]
// grid = 512 blocks, 256 threads (4 waves). 32 rows/block, 8 rows/wave.
// W2 and h in bf16 in LDS (fits 64 KB static-shared limit); additive bank
// swizzle on W2 octs -> 2-way conflicts (free). h2 reuses the h1 buffer.
// ---------------------------------------------------------------------------
__global__ __launch_bounds__(256, 2)
void k_mlp(const float* __restrict__ bmat,
           const float* __restrict__ W1, const float* __restrict__ b1,
           const float* __restrict__ W2, const float* __restrict__ b2,
           const float* __restrict__ W3, const float* __restrict__ b3,
           float* __restrict__ out) {
    __shared__ alignas(16) float sW1[H_ * F_];            // 4096 B
    __shared__ float sB1[H_];                             // 512 B
    __shared__ alignas(16) unsigned short sW2b[H_ * 136]; // 34816 B
    __shared__ float sB2[H_];                             // 512 B
    __shared__ alignas(16) float sW3[O_ * 132];           // 4224 B
    __shared__ float sB3[O_];                             // 32 B
    __shared__ alignas(16) float sB[32 * 8];              // 1024 B
    __shared__ alignas(16) unsigned short sHb[32 * 136];  // 8704 B
    // total ~53.9 KB < 64 KB -> 2 blocks/CU

    const int tid = threadIdx.x;

    // ---- stage weights ----
    for (int i = tid; i < H_ * F_ / 4; i += 256)  // 1 iter
        ((float4*)sW1)[i] = ((const float4*)W1)[i];

    for (int i8 = tid; i8 < H_ * H_ / 8; i8 += 256) {  // 8 iters
        const int idx = i8 * 8;
        const int o = idx >> 7, k = idx & 127;
        const int oct = k >> 3;
        const int octs = (oct & 8) | ((oct + (o & 7)) & 7);  // bank swizzle
        float4 lo = ((const float4*)W2)[i8 * 2];
        float4 hi = ((const float4*)W2)[i8 * 2 + 1];
        uint4 w;
        w.x = f2bf1(lo.x) | (f2bf1(lo.y) << 16);
        w.y = f2bf1(lo.z) | (f2bf1(lo.w) << 16);
        w.z = f2bf1(hi.x) | (f2bf1(hi.y) << 16);
        w.w = f2bf1(hi.z) | (f2bf1(hi.w) << 16);
        *((uint4*)&sW2b[o * 136 + octs * 8]) = w;
    }

    for (int i = tid; i < O_ * H_ / 4; i += 256) {  // 1 iter
        const int idx = i * 4;
        const int o = idx >> 7, k = idx & 127;
        *((float4*)&sW3[o * 132 + k]) = ((const float4*)W3)[i];
    }
    if (tid < H_) { sB1[tid] = b1[tid]; sB2[tid] = b2[tid]; }
    if (tid < O_) sB3[tid] = b3[tid];
    sB[tid] = bmat[(size_t)blockIdx.x * 256 + tid];  // 32 rows * 8
    __syncthreads();

    const int lane = tid & 63;
    const int wv   = tid >> 6;
    const int r0   = wv * 8;  // this wave's 8 rows (block-local)

    // ---- layer 1: h1 = elu(b @ W1^T + b1), outputs o=lane and o=lane+64 ----
    float w1a[8], w1b[8];
    {
        float4 x0 = *(const float4*)&sW1[lane * 8];
        float4 x1 = *(const float4*)&sW1[lane * 8 + 4];
        float4 y0 = *(const float4*)&sW1[(lane + 64) * 8];
        float4 y1 = *(const float4*)&sW1[(lane + 64) * 8 + 4];
        w1a[0]=x0.x; w1a[1]=x0.y; w1a[2]=x0.z; w1a[3]=x0.w;
        w1a[4]=x1.x; w1a[5]=x1.y; w1a[6]=x1.z; w1a[7]=x1.w;
        w1b[0]=y0.x; w1b[1]=y0.y; w1b[2]=y0.z; w1b[3]=y0.w;
        w1b[4]=y1.x; w1b[5]=y1.y; w1b[6]=y1.z; w1b[7]=y1.w;
    }
    const float bias1a = sB1[lane], bias1b = sB1[lane + 64];
#pragma unroll
    for (int r = 0; r < 8; ++r) {
        const float* bp = &sB[(r0 + r) * 8];
        float4 v0 = *(const float4*)bp;
        float4 v1 = *(const float4*)(bp + 4);
        float bv[8] = {v0.x, v0.y, v0.z, v0.w, v1.x, v1.y, v1.z, v1.w};
        float t0 = bias1a, t1 = bias1b;
#pragma unroll
        for (int j = 0; j < 8; ++j) {
            t0 = fmaf(bv[j], w1a[j], t0);
            t1 = fmaf(bv[j], w1b[j], t1);
        }
        sHb[(r0 + r) * 136 + lane]      = (unsigned short)f2bf1(elu(t0));
        sHb[(r0 + r) * 136 + lane + 64] = (unsigned short)f2bf1(elu(t1));
    }
    __syncthreads();

    // ---- layer 2: h2 = elu(h1 @ W2^T + b2) ----
    float acc0[8], acc1[8];
#pragma unroll
    for (int r = 0; r < 8; ++r) { acc0[r] = 0.f; acc1[r] = 0.f; }
    const int swz = lane & 7;
#pragma unroll 1
    for (int oct = 0; oct < 16; ++oct) {
        const int col = ((oct & 8) | ((oct + swz) & 7)) << 3;
        uint4 wa = *(const uint4*)&sW2b[lane * 136 + col];
        uint4 wb = *(const uint4*)&sW2b[(lane + 64) * 136 + col];
        float A[8], Bv[8];
        bf8dec(wa, A);
        bf8dec(wb, Bv);
#pragma unroll
        for (int r = 0; r < 8; ++r) {
            uint4 hw = *(const uint4*)&sHb[(r0 + r) * 136 + (oct << 3)];
            float h[8];
            bf8dec(hw, h);
#pragma unroll
            for (int j = 0; j < 8; ++j) {
                acc0[r] = fmaf(h[j], A[j], acc0[r]);
                acc1[r] = fmaf(h[j], Bv[j], acc1[r]);
            }
        }
    }
    const float bias2a = sB2[lane], bias2b = sB2[lane + 64];
#pragma unroll
    for (int r = 0; r < 8; ++r) {
        sHb[(r0 + r) * 136 + lane]      = (unsigned short)f2bf1(elu(acc0[r] + bias2a));
        sHb[(r0 + r) * 136 + lane + 64] = (unsigned short)f2bf1(elu(acc1[r] + bias2b));
    }
    __syncthreads();

    // ---- layer 3: c = h2 @ W3^T + b3 ; lane -> (row=r0+(lane>>3), o=lane&7)
    const int rr  = lane >> 3;
    const int oo  = lane & 7;
    const int row = r0 + rr;
    float s = 0.f;
#pragma unroll
    for (int oct = 0; oct < 16; ++oct) {
        uint4 hw = *(const uint4*)&sHb[row * 136 + (oct << 3)];
        float h[8];
        bf8dec(hw, h);
        const float* wp = &sW3[oo * 132 + (oct << 3)];
        float4 g0 = *(const float4*)wp;
        float4 g1 = *(const float4*)(wp + 4);
        float g[8] = {g0.x, g0.y, g0.z, g0.w, g1.x, g1.y, g1.z, g1.w};
#pragma unroll
        for (int j = 0; j < 8; ++j) s = fmaf(h[j], g[j], s);
    }
    s += sB3[oo];
    out[(size_t)(blockIdx.x * 32 + row) * 8 + oo] = s;
}

extern "C" void kernel_launch(void* const* d_in, const int* in_sizes, int n_in,
                              void* d_out, int out_size, void* d_ws, size_t ws_size,
                              hipStream_t stream) {
    const float* feat = (const float*)d_in[0];
    const float* adj  = (const float*)d_in[1];
    const float* W1   = (const float*)d_in[2];
    const float* b1   = (const float*)d_in[3];
    const float* W2   = (const float*)d_in[4];
    const float* b2   = (const float*)d_in[5];
    const float* W3   = (const float*)d_in[6];
    const float* b3   = (const float*)d_in[7];
    float* bmat = (float*)d_ws;  // [B*M, 8] = 512 KB
    float* outp = (float*)d_out;

    k_adjfeat<<<dim3(B_ * 256), dim3(256), 0, stream>>>(adj, feat, bmat);
    k_mlp<<<dim3(512), dim3(256), 0, stream>>>(bmat, W1, b1, W2, b2, W3, b3, outp);
}

// Round 2
// 396.286 us; speedup vs baseline: 1.0069x; 1.0069x over previous
//
#include <hip/hip_runtime.h>
#include <cstdint>
#include <cstddef>

#define B_ 4
#define M_ 4096
#define N_ 4096
#define F_ 8
#define H_ 128
#define O_ 8

// round-to-nearest-even float -> bf16 (as uint16 in low bits)
__device__ __forceinline__ uint32_t f2bf1(float x) {
    uint32_t u = __float_as_uint(x);
    return (u + 0x7fffu + ((u >> 16) & 1u)) >> 16;
}

// decode 8 packed bf16 (uint4) -> 8 floats; f[0] is low half of w.x
__device__ __forceinline__ void bf8dec(uint4 w, float* f) {
    f[0] = __uint_as_float(w.x << 16);
    f[1] = __uint_as_float(w.x & 0xffff0000u);
    f[2] = __uint_as_float(w.y << 16);
    f[3] = __uint_as_float(w.y & 0xffff0000u);
    f[4] = __uint_as_float(w.z << 16);
    f[5] = __uint_as_float(w.z & 0xffff0000u);
    f[6] = __uint_as_float(w.w << 16);
    f[7] = __uint_as_float(w.w & 0xffff0000u);
}

__device__ __forceinline__ float elu(float x) {
    return x > 0.f ? x : (__expf(x) - 1.f);
}

// ---------------------------------------------------------------------------
// Fused kernel: per block (one batch, 16 rows of adj):
//   Phase A: b[16][8] = adj[rows] @ feat   (feat staged bf16 in 64 KB LDS,
//            fp32 accumulate, butterfly reduce -> every lane of wave wv holds
//            all 4 of its rows' b-values in registers)
//   Phase B: alias the (now dead) feat LDS with the MLP weights and run the
//            3-layer MLP on the wave-private rows; write c directly to out.
// grid = B*256 blocks, 256 threads (4 waves), 2 blocks/CU.
// ---------------------------------------------------------------------------
__global__ __launch_bounds__(256, 2)
void k_fused(const float* __restrict__ adj, const float* __restrict__ feat,
             const float* __restrict__ W1, const float* __restrict__ b1,
             const float* __restrict__ W2, const float* __restrict__ b2,
             const float* __restrict__ W3, const float* __restrict__ b3,
             float* __restrict__ out) {
    __shared__ alignas(16) unsigned char smem[65536];
    // phase A view
    uint4* sfeat = (uint4*)smem;  // 4096 * 16B = 64 KB
    // phase B view (all 16B-aligned offsets)
    float* sW1 = (float*)smem;                          // [128*8]   4096 B
    float* sW3 = (float*)(smem + 4096);                 // [8*132]   4224 B
    float* sB1 = (float*)(smem + 8320);                 // [128]      512 B
    float* sB2 = (float*)(smem + 8832);                 // [128]      512 B
    float* sB3 = (float*)(smem + 9344);                 // [8]         32 B
    float* sH  = (float*)(smem + 9376);                 // [16*132]  8448 B
    unsigned short* sW2b = (unsigned short*)(smem + 17824); // [128*136] bf16, 34816 B
    // total phase-B footprint 52640 B < 65536

    const int tid = threadIdx.x;
    const int bb  = blockIdx.x >> 8;   // batch
    const int rb  = blockIdx.x & 255;  // row-block (16 rows)

    // ---- stage feat[bb] -> bf16 LDS (4-plane layout: plane k = n%4==k) ----
    const float4* fsrc = (const float4*)(feat + (size_t)bb * (N_ * F_));
    for (int n = tid; n < N_; n += 256) {
        float4 lo = fsrc[2 * n];
        float4 hi = fsrc[2 * n + 1];
        uint4 w;
        w.x = f2bf1(lo.x) | (f2bf1(lo.y) << 16);
        w.y = f2bf1(lo.z) | (f2bf1(lo.w) << 16);
        w.z = f2bf1(hi.x) | (f2bf1(hi.y) << 16);
        w.w = f2bf1(hi.z) | (f2bf1(hi.w) << 16);
        sfeat[(n & 3) * 1024 + (n >> 2)] = w;
    }
    __syncthreads();

    const int lane = tid & 63;
    const int wv   = tid >> 6;
    const int m0   = rb * 16 + wv * 4;  // this wave's 4 rows

    const float4* arow = (const float4*)(adj + (size_t)(bb * M_ + m0) * N_);

    float acc[4][8];
#pragma unroll
    for (int r = 0; r < 4; ++r)
#pragma unroll
        for (int f = 0; f < 8; ++f) acc[r][f] = 0.f;

#pragma unroll 1
    for (int c = 0; c < 16; ++c) {
        const int ni = (c << 6) + lane;  // float4 index within the row
        float4 a0 = arow[ni];
        float4 a1 = arow[ni + 1024];
        float4 a2 = arow[ni + 2048];
        float4 a3 = arow[ni + 3072];
        uint4 w0 = sfeat[ni];
        uint4 w1 = sfeat[1024 + ni];
        uint4 w2 = sfeat[2048 + ni];
        uint4 w3 = sfeat[3072 + ni];

        float av[4][4] = {{a0.x, a1.x, a2.x, a3.x},
                          {a0.y, a1.y, a2.y, a3.y},
                          {a0.z, a1.z, a2.z, a3.z},
                          {a0.w, a1.w, a2.w, a3.w}};
        uint4 ww[4] = {w0, w1, w2, w3};
#pragma unroll
        for (int k = 0; k < 4; ++k) {
            float f[8];
            bf8dec(ww[k], f);
#pragma unroll
            for (int r = 0; r < 4; ++r) {
                const float a = av[k][r];
#pragma unroll
                for (int j = 0; j < 8; ++j)
                    acc[r][j] = fmaf(a, f[j], acc[r][j]);
            }
        }
    }

    // ---- 64-lane butterfly: every lane ends with the full sums for its
    //      wave's 4 rows x 8 features ----
#pragma unroll
    for (int r = 0; r < 4; ++r)
#pragma unroll
        for (int j = 0; j < 8; ++j) {
            float v = acc[r][j];
            v += __shfl_xor(v, 32, 64);
            v += __shfl_xor(v, 16, 64);
            v += __shfl_xor(v, 8, 64);
            v += __shfl_xor(v, 4, 64);
            v += __shfl_xor(v, 2, 64);
            v += __shfl_xor(v, 1, 64);
            acc[r][j] = v;
        }

    __syncthreads();  // sfeat dead -> safe to overwrite with weights

    // ---- stage MLP weights into the aliased LDS ----
    for (int i = tid; i < H_ * F_ / 4; i += 256)  // 1 iter
        ((float4*)sW1)[i] = ((const float4*)W1)[i];

    for (int i8 = tid; i8 < H_ * H_ / 8; i8 += 256) {  // 8 iters
        const int idx = i8 * 8;
        const int o = idx >> 7, k = idx & 127;
        float4 lo = ((const float4*)W2)[i8 * 2];
        float4 hi = ((const float4*)W2)[i8 * 2 + 1];
        uint4 w;
        w.x = f2bf1(lo.x) | (f2bf1(lo.y) << 16);
        w.y = f2bf1(lo.z) | (f2bf1(lo.w) << 16);
        w.z = f2bf1(hi.x) | (f2bf1(hi.y) << 16);
        w.w = f2bf1(hi.z) | (f2bf1(hi.w) << 16);
        // row stride 136 shorts = 272 B = 17 x 16B units -> lane-varying b128
        // reads are bank-spread (17 mod 8 = 1), no swizzle needed
        *((uint4*)&sW2b[o * 136 + k]) = w;
    }

    for (int i = tid; i < O_ * H_ / 4; i += 256) {  // 1 iter (i<256)
        const int idx = i * 4;
        const int o = idx >> 7, k = idx & 127;
        *((float4*)&sW3[o * 132 + k]) = ((const float4*)W3)[i];
    }
    if (tid < H_) { sB1[tid] = b1[tid]; sB2[tid] = b2[tid]; }
    if (tid < O_) sB3[tid] = b3[tid];
    __syncthreads();

    // ---- layer 1: h1 = elu(b @ W1^T + b1); lane covers o=lane, o=lane+64;
    //      b-values are already in registers (acc) ----
    float w1a[8], w1b[8];
    {
        float4 x0 = *(const float4*)&sW1[lane * 8];
        float4 x1 = *(const float4*)&sW1[lane * 8 + 4];
        float4 y0 = *(const float4*)&sW1[(lane + 64) * 8];
        float4 y1 = *(const float4*)&sW1[(lane + 64) * 8 + 4];
        w1a[0]=x0.x; w1a[1]=x0.y; w1a[2]=x0.z; w1a[3]=x0.w;
        w1a[4]=x1.x; w1a[5]=x1.y; w1a[6]=x1.z; w1a[7]=x1.w;
        w1b[0]=y0.x; w1b[1]=y0.y; w1b[2]=y0.z; w1b[3]=y0.w;
        w1b[4]=y1.x; w1b[5]=y1.y; w1b[6]=y1.z; w1b[7]=y1.w;
    }
    const float bias1a = sB1[lane], bias1b = sB1[lane + 64];
#pragma unroll
    for (int r = 0; r < 4; ++r) {
        float t0 = bias1a, t1 = bias1b;
#pragma unroll
        for (int j = 0; j < 8; ++j) {
            t0 = fmaf(acc[r][j], w1a[j], t0);
            t1 = fmaf(acc[r][j], w1b[j], t1);
        }
        // rows are wave-private: no cross-wave hazard, no barrier needed
        sH[(wv * 4 + r) * 132 + lane]      = elu(t0);
        sH[(wv * 4 + r) * 132 + lane + 64] = elu(t1);
    }

    // ---- layer 2: h2 = elu(h1 @ W2^T + b2) ----
    float a20[4], a21[4];
#pragma unroll
    for (int r = 0; r < 4; ++r) { a20[r] = 0.f; a21[r] = 0.f; }
#pragma unroll 1
    for (int oct = 0; oct < 16; ++oct) {
        uint4 wa = *(const uint4*)&sW2b[lane * 136 + (oct << 3)];
        uint4 wb = *(const uint4*)&sW2b[(lane + 64) * 136 + (oct << 3)];
        float A[8], Bv[8];
        bf8dec(wa, A);
        bf8dec(wb, Bv);
#pragma unroll
        for (int r = 0; r < 4; ++r) {
            // same address across the wave -> LDS broadcast, conflict-free
            const float* hp = &sH[(wv * 4 + r) * 132 + (oct << 3)];
            float4 h0 = *(const float4*)hp;
            float4 h1v = *(const float4*)(hp + 4);
            float hv[8] = {h0.x, h0.y, h0.z, h0.w, h1v.x, h1v.y, h1v.z, h1v.w};
#pragma unroll
            for (int j = 0; j < 8; ++j) {
                a20[r] = fmaf(hv[j], A[j], a20[r]);
                a21[r] = fmaf(hv[j], Bv[j], a21[r]);
            }
        }
    }
    const float bias2a = sB2[lane], bias2b = sB2[lane + 64];
#pragma unroll
    for (int r = 0; r < 4; ++r) {
        // all reads of h1 for this wave's rows completed above; overwrite in place
        sH[(wv * 4 + r) * 132 + lane]      = elu(a20[r] + bias2a);
        sH[(wv * 4 + r) * 132 + lane + 64] = elu(a21[r] + bias2b);
    }

    // ---- layer 3: c = h2 @ W3^T + b3; lanes 0..31: row=lane>>3, o=lane&7 ----
    if (lane < 32) {
        const int rr = lane >> 3;
        const int oo = lane & 7;
        const float* hp = &sH[(wv * 4 + rr) * 132];
        const float* wp = &sW3[oo * 132];
        float s = sB3[oo];
#pragma unroll
        for (int k = 0; k < 128; k += 4) {
            float4 h = *(const float4*)(hp + k);
            float4 g = *(const float4*)(wp + k);
            s = fmaf(h.x, g.x, fmaf(h.y, g.y, fmaf(h.z, g.z, fmaf(h.w, g.w, s))));
        }
        out[(size_t)(bb * M_ + m0 + rr) * 8 + oo] = s;  // 128 B/wave, coalesced
    }
}

extern "C" void kernel_launch(void* const* d_in, const int* in_sizes, int n_in,
                              void* d_out, int out_size, void* d_ws, size_t ws_size,
                              hipStream_t stream) {
    const float* feat = (const float*)d_in[0];
    const float* adj  = (const float*)d_in[1];
    const float* W1   = (const float*)d_in[2];
    const float* b1   = (const float*)d_in[3];
    const float* W2   = (const float*)d_in[4];
    const float* b2   = (const float*)d_in[5];
    const float* W3   = (const float*)d_in[6];
    const float* b3   = (const float*)d_in[7];
    float* outp = (float*)d_out;

    k_fused<<<dim3(B_ * 256), dim3(256), 0, stream>>>(
        adj, feat, W1, b1, W2, b2, W3, b3, outp);
}